// Round 9
// baseline (355.694 us; speedup 1.0000x reference)
//
#include <hip/hip_runtime.h>

// GCN: n=100k nodes, E=1.6M edges, D=64, 3 layers.
// Round 17: fine buckets + LDS-staged sort + cast fusion. R16 fixed scatter
// (coalesced multi-split, dropped below top-5); spmm_gemm invariant at 74.8us
// (L2-miss-bound, proven R12). sort_place kept 391 blocks = 1.5 blocks/CU.
// Now: 782 buckets x 128 rows (pack (src<<7)|(dst&127), CAPB 4096 = mean+45sigma),
// sort_place stages the whole bucket in LDS (one global read, no fallback),
// fuses the bf16 cast (cast_xb deleted). scatter: 1024-bin hist/scan.
// Needs n <= 2^17 (pack) and nbb <= 1024.

#define CAPB 4096      // per-bucket slot capacity (mean 2046, sigma 45 -> +45 sigma)
#define CPAD 16        // cursor stride in ints: one counter per 64B cache line

__device__ __forceinline__ unsigned short f2bf(float f) {   // RNE fp32->bf16
  unsigned u = __float_as_uint(f);
  u += 0x7fff + ((u >> 16) & 1);
  return (unsigned short)(u >> 16);
}
__device__ __forceinline__ float bflo(unsigned u) { return __uint_as_float(u << 16); }
__device__ __forceinline__ float bfhi(unsigned u) { return __uint_as_float(u & 0xffff0000u); }

// ---------------- init: padded cursors cur_d/cur_s [b*CPAD] = b*CAPB ----------------
__global__ void init_zero(int* __restrict__ cur_d, int* __restrict__ cur_s) {
  int idx = blockIdx.x * 256 + threadIdx.x;
  if (idx < 1024 * CPAD) {
    int v = (idx % CPAD == 0) ? (idx / CPAD) * CAPB : 0;
    cur_d[idx] = v;
    cur_s[idx] = v;
  }
}

// ---------------- one read pass, two LDS-staged coalesced splits (1024 bins) ----------------
// 1024 threads x 4 edges = 4096 edges/block. Split 1: by dst bucket -> edges1 words
// (src<<7)|(dst&127). Split 2: by src bucket -> srcbuf bytes (src&127).
__global__ __launch_bounds__(1024) void scatter_both(
    const int* __restrict__ src, const int* __restrict__ dst, int e,
    int* __restrict__ cur_d, int* __restrict__ cur_s,
    unsigned* __restrict__ edges1, unsigned char* __restrict__ srcbuf) {
  __shared__ int stW[4096], stG[4096];
  __shared__ int hist[1024], curL[1024], gofs[1024], psum[1024];
  int t = threadIdx.x, b = blockIdx.x;
  int i0 = b * 4096 + 4 * t;
  int sv[4], dv[4];
  if (i0 + 3 < e) {
    int4 s4 = *(const int4*)&src[i0];
    int4 d4 = *(const int4*)&dst[i0];
    sv[0] = s4.x; sv[1] = s4.y; sv[2] = s4.z; sv[3] = s4.w;
    dv[0] = d4.x; dv[1] = d4.y; dv[2] = d4.z; dv[3] = d4.w;
  } else {
    #pragma unroll
    for (int j = 0; j < 4; j++) {
      int idx = i0 + j;
      if (idx < e) { sv[j] = src[idx]; dv[j] = dst[idx]; }
      else { sv[j] = -1; dv[j] = -1; }
    }
  }
  // ======== split 1: by dst bucket ========
  hist[t] = 0;
  __syncthreads();
  #pragma unroll
  for (int k = 0; k < 4; k++)
    if (dv[k] >= 0) atomicAdd(&hist[dv[k] >> 7], 1);
  __syncthreads();
  psum[t] = hist[t];
  __syncthreads();
  for (int off = 1; off < 1024; off <<= 1) {
    int a = (t >= off) ? psum[t - off] : 0;
    __syncthreads();
    psum[t] += a;
    __syncthreads();
  }
  {
    int cnt = hist[t];
    int base = psum[t] - cnt;
    curL[t] = base;
    int g = cnt ? atomicAdd(&cur_d[t * CPAD], cnt) : 0;
    gofs[t] = g - base;
  }
  __syncthreads();
  #pragma unroll
  for (int k = 0; k < 4; k++) {
    if (dv[k] >= 0) {
      int bin = dv[k] >> 7;
      int r = atomicAdd(&curL[bin], 1);
      stW[r] = (sv[k] << 7) | (dv[k] & 127);
      stG[r] = gofs[bin] + r;
    }
  }
  __syncthreads();
  int tot = psum[1023];
  for (int idx = t; idx < tot; idx += 1024)
    edges1[stG[idx]] = (unsigned)stW[idx];      // coalesced within bucket runs
  __syncthreads();
  // ======== split 2: by src bucket (byte payload) ========
  hist[t] = 0;
  __syncthreads();
  #pragma unroll
  for (int k = 0; k < 4; k++)
    if (dv[k] >= 0) atomicAdd(&hist[sv[k] >> 7], 1);
  __syncthreads();
  psum[t] = hist[t];
  __syncthreads();
  for (int off = 1; off < 1024; off <<= 1) {
    int a = (t >= off) ? psum[t - off] : 0;
    __syncthreads();
    psum[t] += a;
    __syncthreads();
  }
  {
    int cnt = hist[t];
    int base = psum[t] - cnt;
    curL[t] = base;
    int g = cnt ? atomicAdd(&cur_s[t * CPAD], cnt) : 0;
    gofs[t] = g - base;
  }
  __syncthreads();
  #pragma unroll
  for (int k = 0; k < 4; k++) {
    if (dv[k] >= 0) {
      int bin = sv[k] >> 7;
      int r = atomicAdd(&curL[bin], 1);
      stW[r] = sv[k] & 127;
      stG[r] = gofs[bin] + r;
    }
  }
  __syncthreads();
  for (int idx = t; idx < tot; idx += 1024)
    srcbuf[stG[idx]] = (unsigned char)stW[idx]; // coalesced byte runs
}

// ---------------- per-bucket: LDS-staged sort + degrees + row_be + fused bf16 cast ----------
// block b owns nodes [b*128, +128); dst slot [b*CAPB, cur_d[b*CPAD)) words (<= CAPB);
// src slot [b*CAPB, cur_s[b*CPAD)) bytes. 512 threads, 782 blocks.
__global__ __launch_bounds__(512) void sort_place(
    const unsigned* __restrict__ edges1, const unsigned char* __restrict__ srcbuf,
    const int* __restrict__ cur_d, const int* __restrict__ cur_s,
    const float* __restrict__ node_feat,
    int2* __restrict__ row_be, float* __restrict__ inv_in, float* __restrict__ inv_out,
    unsigned short* __restrict__ xb, int* __restrict__ col, int n) {
  __shared__ int sEdge[CAPB];         // 16 KB staged bucket edges
  __shared__ int sOut[CAPB];          // 16 KB sorted src ids
  __shared__ int hist[128], cur[128], psum[128], dhist[128];
  __shared__ float sInvO[128];
  int b = blockIdx.x, t = threadIdx.x;
  int sbase = b * CAPB;
  int m = cur_d[b * CPAD] - sbase;    // bucket edge count (<= CAPB)
  int ms = cur_s[b * CPAD] - sbase;   // src-side byte count
  int rstart = b << 7;
  int nrows = min(128, n - rstart);
  if (t < 128) { hist[t] = 0; dhist[t] = 0; }
  __syncthreads();
  // stage edges in LDS + out-degree histogram from byte buffer (one global pass each)
  for (int k = t; k < m; k += 512) sEdge[k] = (int)edges1[sbase + k];
  for (int k = t; k < ms; k += 512) atomicAdd(&dhist[srcbuf[sbase + k]], 1);
  __syncthreads();
  // in-degree histogram from LDS
  for (int k = t; k < m; k += 512) atomicAdd(&hist[sEdge[k] & 127], 1);
  __syncthreads();
  int h0 = 0;
  if (t < 128) { h0 = hist[t]; psum[t] = h0; }
  __syncthreads();
  for (int off = 1; off < 128; off <<= 1) {
    int a = 0;
    if (t < 128 && t >= off) a = psum[t - off];
    __syncthreads();
    if (t < 128) psum[t] += a;
    __syncthreads();
  }
  if (t < 128) {
    int ex = psum[t] - h0;
    float ivo = rsqrtf(fmaxf((float)dhist[t], 1.0f));
    sInvO[t] = ivo;
    if (t < nrows) {
      row_be[rstart + t] = make_int2(sbase + ex, sbase + ex + h0);
      inv_in[rstart + t] = rsqrtf(fmaxf((float)h0, 1.0f));
      inv_out[rstart + t] = ivo;
    }
    cur[t] = ex;
  }
  __syncthreads();
  // place (LDS -> LDS; pos < m <= CAPB always)
  for (int k = t; k < m; k += 512) {
    int v = sEdge[k];
    int pos = atomicAdd(&cur[v & 127], 1);
    sOut[pos] = v >> 7;
  }
  __syncthreads();
  for (int k = t; k < m; k += 512) col[sbase + k] = sOut[k];
  // fused pre-scaled bf16 cast of this bucket's feature rows
  int total4 = nrows * 16;            // 16 float4 per row
  const float4* nf4 = (const float4*)(node_feat + (size_t)rstart * 64);
  ushort4* xb4 = (ushort4*)(xb + (size_t)rstart * 64);
  for (int u = t; u < total4; u += 512) {
    float iv = sInvO[u >> 4];
    float4 v = nf4[u];
    ushort4 o;
    o.x = f2bf(v.x * iv); o.y = f2bf(v.y * iv);
    o.z = f2bf(v.z * iv); o.w = f2bf(v.w * iv);
    xb4[u] = o;
  }
}

// ---------------- fused SpMM + GEMM + bias + ReLU + pool + next-layer bf16 cast ----------------
// 512 threads own 64 rows. Phase 1: 8 waves x 8 rows, wave-per-row gather (16 edges
// in flight, degree-adaptive), shfl-reduce, scaled store into transposed LDS tile sXT.
// Phase 2: 64x64 @ 64x64 GEMM (W from global, L1/L2-resident) with epilogue.
__global__ __launch_bounds__(512) void spmm_gemm(
    const unsigned short* __restrict__ xb,
    const int2* __restrict__ row_be,
    const int* __restrict__ col,
    const float* __restrict__ inv_in, const float* __restrict__ inv_out,
    const float* __restrict__ W, const float* __restrict__ bias,
    float* __restrict__ out_cat, float* __restrict__ out_pool,
    unsigned short* __restrict__ xb_next, int n) {
  __shared__ float sXT[64][68];       // [feat][row], pad 68 (272B stride, 8B-aligned)
  int t = threadIdx.x;
  int row0 = blockIdx.x << 6;         // 64 rows per block
  int lane = t & 63;
  int g = lane >> 3;            // edge group 0..7
  int l8 = (lane & 7) << 3;     // feature offset (8 feats = 16 B)
  int wv = t >> 6;              // wave 0..7, each owns 8 rows
  for (int k = 0; k < 8; k++) {
    int rl = wv * 8 + k;
    int row = row0 + rl;
    float v = 0.f;
    if (row < n) {              // wave-uniform branch
      int2 be = row_be[row];    // one 8B load: [beg, end)
      int s = be.x, e = be.y;
      float inv = inv_in[row];  // hoisted: overlaps with the edge loop below
      float a0 = 0, a1 = 0, a2 = 0, a3 = 0, a4 = 0, a5 = 0, a6 = 0, a7 = 0;
      int ec = e - 1;
      for (int i = s + g; i < e; i += 16) {   // 16 edges in flight, deg-adaptive
        int i1 = i + 8;
        int c0 = col[i];
        int c1 = col[min(i1, ec)];
        float m1 = (i1 < e) ? 1.f : 0.f;
        uint4 r0 = *(const uint4*)&xb[(size_t)c0 * 64 + l8];
        uint4 r1 = *(const uint4*)&xb[(size_t)c1 * 64 + l8];
        a0 += bflo(r0.x); a1 += bfhi(r0.x); a2 += bflo(r0.y); a3 += bfhi(r0.y);
        a4 += bflo(r0.z); a5 += bfhi(r0.z); a6 += bflo(r0.w); a7 += bfhi(r0.w);
        a0 = fmaf(m1, bflo(r1.x), a0); a1 = fmaf(m1, bfhi(r1.x), a1);
        a2 = fmaf(m1, bflo(r1.y), a2); a3 = fmaf(m1, bfhi(r1.y), a3);
        a4 = fmaf(m1, bflo(r1.z), a4); a5 = fmaf(m1, bfhi(r1.z), a5);
        a6 = fmaf(m1, bflo(r1.w), a6); a7 = fmaf(m1, bfhi(r1.w), a7);
      }
      // butterfly over edge groups (bits 3..5 of lane): all lanes end with full sums
      a0 += __shfl_xor(a0, 8); a0 += __shfl_xor(a0, 16); a0 += __shfl_xor(a0, 32);
      a1 += __shfl_xor(a1, 8); a1 += __shfl_xor(a1, 16); a1 += __shfl_xor(a1, 32);
      a2 += __shfl_xor(a2, 8); a2 += __shfl_xor(a2, 16); a2 += __shfl_xor(a2, 32);
      a3 += __shfl_xor(a3, 8); a3 += __shfl_xor(a3, 16); a3 += __shfl_xor(a3, 32);
      a4 += __shfl_xor(a4, 8); a4 += __shfl_xor(a4, 16); a4 += __shfl_xor(a4, 32);
      a5 += __shfl_xor(a5, 8); a5 += __shfl_xor(a5, 16); a5 += __shfl_xor(a5, 32);
      a6 += __shfl_xor(a6, 8); a6 += __shfl_xor(a6, 16); a6 += __shfl_xor(a6, 32);
      a7 += __shfl_xor(a7, 8); a7 += __shfl_xor(a7, 16); a7 += __shfl_xor(a7, 32);
      // lane (g,l8) contributes feature f = l8 + g (cndmask tree, no scratch array)
      float s0 = (g & 1) ? a1 : a0;
      float s1 = (g & 1) ? a3 : a2;
      float s2 = (g & 1) ? a5 : a4;
      float s3 = (g & 1) ? a7 : a6;
      float u0 = (g & 2) ? s1 : s0;
      float u1 = (g & 2) ? s3 : s2;
      v = ((g & 4) ? u1 : u0) * inv;
    }
    sXT[l8 + g][rl] = v;        // 64 lanes -> 64 feats of column rl (8-way, single store)
  }
  __syncthreads();
  // ---- GEMM phase: 512 threads, 2x4 micro-tile each -> 64 rows x 64 cols ----
  int tj = t & 15, tr = t >> 4;       // tj: col group 0..15, tr: row group 0..31
  int j4 = tj << 2, r2 = tr << 1;
  const float4 bv = *(const float4*)&bias[j4];
  float4 a0 = bv, a1 = bv;
  #pragma unroll 8
  for (int f = 0; f < 64; f++) {
    float4 w  = *(const float4*)&W[f * 64 + j4];   // L1-resident after first block
    float2 xv = *(const float2*)&sXT[f][r2];
    a0.x = fmaf(xv.x, w.x, a0.x); a0.y = fmaf(xv.x, w.y, a0.y);
    a0.z = fmaf(xv.x, w.z, a0.z); a0.w = fmaf(xv.x, w.w, a0.w);
    a1.x = fmaf(xv.y, w.x, a1.x); a1.y = fmaf(xv.y, w.y, a1.y);
    a1.z = fmaf(xv.y, w.z, a1.z); a1.w = fmaf(xv.y, w.w, a1.w);
  }
  float4 accs[2] = {a0, a1};
  #pragma unroll
  for (int ri = 0; ri < 2; ri++) {
    int row = row0 + r2 + ri;
    if (row < n) {
      float4 h = accs[ri];
      h.x = fmaxf(h.x, 0.f); h.y = fmaxf(h.y, 0.f);
      h.z = fmaxf(h.z, 0.f); h.w = fmaxf(h.w, 0.f);
      *(float4*)&out_cat[(size_t)row * 192 + j4] = h;
      if (xb_next) {
        float sc = inv_out[row];
        ushort4 o;
        o.x = f2bf(h.x * sc); o.y = f2bf(h.y * sc);
        o.z = f2bf(h.z * sc); o.w = f2bf(h.w * sc);
        *(ushort4*)&xb_next[(size_t)row * 64 + j4] = o;
      }
      float part = h.x + h.y + h.z + h.w;
      part += __shfl_xor(part, 1);
      part += __shfl_xor(part, 2);
      part += __shfl_xor(part, 4);
      part += __shfl_xor(part, 8);
      if (tj == 0) out_pool[row] = part;
    }
  }
}

// ---------------- launch ----------------

extern "C" void kernel_launch(void* const* d_in, const int* in_sizes, int n_in,
                              void* d_out, int out_size, void* d_ws, size_t ws_size,
                              hipStream_t stream) {
  const float* node_feat = (const float*)d_in[0];
  const int* src = (const int*)d_in[1];
  const int* dst = (const int*)d_in[2];
  const float* Ws[3] = {(const float*)d_in[4], (const float*)d_in[6], (const float*)d_in[8]};
  const float* bs[3] = {(const float*)d_in[5], (const float*)d_in[7], (const float*)d_in[9]};
  float* out = (float*)d_out;
  int n = in_sizes[0] / 64;
  int e = in_sizes[1];
  int nbb = (n + 127) >> 7;         // buckets of 128 rows (782 for n=100k)
  int nblk = (e + 4095) / 4096;     // edge blocks (391)
  size_t slots = (size_t)nbb * CAPB;

  char* p = (char*)d_ws;
  unsigned short* xba = (unsigned short*)p; p += (size_t)n * 64 * sizeof(unsigned short);
  unsigned short* xbb = (unsigned short*)p; p += (size_t)n * 64 * sizeof(unsigned short);
  float* inv_out = (float*)p;   p += (size_t)n * sizeof(float);
  float* inv_in = (float*)p;    p += (size_t)n * sizeof(float);
  int2* row_be = (int2*)p;      p += (size_t)n * sizeof(int2);
  int* cur_d = (int*)p;         p += 1024 * CPAD * sizeof(int);
  int* cur_s = (int*)p;         p += 1024 * CPAD * sizeof(int);
  unsigned* edges1 = (unsigned*)p; p += slots * sizeof(unsigned);
  int* col = (int*)p;           p += slots * sizeof(int);
  unsigned char* srcbuf = (unsigned char*)p; p += slots;

  init_zero<<<64, 256, 0, stream>>>(cur_d, cur_s);
  scatter_both<<<nblk, 1024, 0, stream>>>(src, dst, e, cur_d, cur_s, edges1, srcbuf);
  sort_place<<<nbb, 512, 0, stream>>>(edges1, srcbuf, cur_d, cur_s, node_feat,
                                      row_be, inv_in, inv_out, xba, col, n);

  float* cat_base = out + (size_t)3 * n;
  int nfb = (n + 63) >> 6;          // fused blocks: 64 rows each (1563 for n=100k)
  // xb double-buffered: fused kernel reads features while writing next layer's.
  spmm_gemm<<<nfb, 512, 0, stream>>>(xba, row_be, col, inv_in, inv_out,
      Ws[0], bs[0], cat_base + 0 * 64, out + (size_t)0 * n, xbb, n);
  spmm_gemm<<<nfb, 512, 0, stream>>>(xbb, row_be, col, inv_in, inv_out,
      Ws[1], bs[1], cat_base + 1 * 64, out + (size_t)1 * n, xba, n);
  spmm_gemm<<<nfb, 512, 0, stream>>>(xba, row_be, col, inv_in, inv_out,
      Ws[2], bs[2], cat_base + 2 * 64, out + (size_t)2 * n, (unsigned short*)nullptr, n);
}